// Round 15
// baseline (205.489 us; speedup 1.0000x reference)
//
#include <hip/hip_runtime.h>
#include <hip/hip_bf16.h>
#include <stdint.h>

// ---------------------------------------------------------------------------
// Co-Guiding GAT forward: 2 layers x 4 masked-MHA branches, B=4 N=1024 D=256
// H=8 dk=32.
// R15: (1) attn: s_setprio(1) around MFMA clusters (T5, m191 +4-7% attn);
// (2) gemm_k: B-panel read DIRECT from global (L2-resident, zero cross-wave
// reuse made LDS staging pure overhead); (3) opln_k: same B-direct (LDS
// 76.8->20KB).  Rest identical to R14.
// ---------------------------------------------------------------------------

using bf16x8 = __attribute__((ext_vector_type(8))) short;   // 8 bf16 (4 VGPRs)
using f32x4  = __attribute__((ext_vector_type(4))) float;
using f32x16 = __attribute__((ext_vector_type(16))) float;

#define DEVI __device__ __forceinline__

DEVI uint16_t f2bf(float x) {                 // RNE f32 -> bf16 bits (scalar)
  uint32_t u = __float_as_uint(x);
  u += 0x7FFFu + ((u >> 16) & 1u);
  return (uint16_t)(u >> 16);
}
DEVI uint32_t packbf2(float lo, float hi) {   // hw v_cvt_pk_bf16_f32 via API
  union { __hip_bfloat162 h; uint32_t u; } cv;
  cv.h = __float22bfloat162_rn(make_float2(lo, hi));
  return cv.u;
}
DEVI float bf2f(uint16_t v) { return __uint_as_float((uint32_t)v << 16); }
DEVI int phi4(int m) {                        // swap bits 2<->3 (involution)
  return ((m & 4) << 1) | ((m & 8) >> 1) | (m & 3);
}

// ---------------------------------------------------------------------------
// Merged prep: blocks [0,512) weight transpose+cvt; [512,1536) input cvt;
// [1536,67072) adjacency -> transposed bitmask.
// ---------------------------------------------------------------------------
struct PrepArgs {
  const float* Wq; const float* Wk; const float* Wv; const float* Wo;
  uint16_t* wt;
  const float* ha; const float* hb;
  uint16_t* oa; uint16_t* ob;
  const int* adj[4];
  uint32_t* bits[4];
};

__global__ __launch_bounds__(256) void prep_k(PrepArgs a) {
  const int blk = blockIdx.x;
  const int t = threadIdx.x;
  __shared__ float tl[64][68];

  if (blk < 512) {               // ---- weight prep ----
    const int bx = blk & 3, by = (blk >> 2) & 3, z = blk >> 4;
    const int type = z >> 3, mat = z & 7;
    const float* W = (type == 0 ? a.Wq : type == 1 ? a.Wk : type == 2 ? a.Wv : a.Wo)
                     + (size_t)mat * 65536;
    uint16_t* o = a.wt + (size_t)type * 524288 + (size_t)mat * 65536;
    const int r0 = by * 64, c0 = bx * 64;
    {
      const int rr = t >> 2, cb = (t & 3) * 16;
      const float* src = W + (size_t)(r0 + rr) * 256 + c0 + cb;
      #pragma unroll
      for (int q = 0; q < 4; ++q) {
        float4 v = *(const float4*)(src + q * 4);
        tl[rr][cb + q*4 + 0] = v.x; tl[rr][cb + q*4 + 1] = v.y;
        tl[rr][cb + q*4 + 2] = v.z; tl[rr][cb + q*4 + 3] = v.w;
      }
    }
    __syncthreads();
    {
      const int nn = t >> 2, kb = (t & 3) * 16;
      __align__(16) uint16_t tmp[16];
      #pragma unroll
      for (int q = 0; q < 16; ++q) tmp[q] = f2bf(tl[kb + q][nn]);
      uint16_t* dst = o + (size_t)(c0 + nn) * 256 + r0 + kb;
      *(uint4*)&dst[0] = *(uint4*)&tmp[0];
      *(uint4*)&dst[8] = *(uint4*)&tmp[8];
    }
  } else if (blk < 1536) {       // ---- input fp32->bf16 ----
    const int idx = blk - 512;
    const int bx = idx & 511, by = idx >> 9;
    const size_t i = ((size_t)bx * 256 + t) * 8;
    const float* s = by ? a.hb : a.ha;
    uint16_t* o = by ? a.ob : a.oa;
    const float4 f0 = *(const float4*)(s + i), f1 = *(const float4*)(s + i + 4);
    uint4 u;
    u.x = packbf2(f0.x, f0.y); u.y = packbf2(f0.z, f0.w);
    u.z = packbf2(f1.x, f1.y); u.w = packbf2(f1.z, f1.w);
    *(uint4*)(o + i) = u;
  } else {                       // ---- adj -> bitmask ----
    const int idx = blk - 1536;
    const int bx = idx & 16383, z = idx >> 14;
    const int* adj = a.adj[z];
    uint32_t* bits = a.bits[z];
    const size_t i = (size_t)bx * 256 + t;
    const int lane = t & 63;
    const int v = adj[i];
    unsigned long long m = __ballot(v != 0);
    if ((lane & 31) == 0) {
      const uint32_t wi = (uint32_t)(i >> 5);      // (b*1024+q)*32 + kw
      const uint32_t kw = wi & 31;
      const uint32_t q  = (wi >> 5) & 1023;
      const uint32_t bb = wi >> 15;
      bits[((bb * 32 + kw) << 10) | q] = (uint32_t)(m >> (lane & 32));
    }
  }
}

// ---------------------------------------------------------------------------
// GEMM (QKV): C = (Abf @ W + bias) * os.  A: LDS double-buffered (gload_lds,
// source-pre-swizzled).  B: DIRECT global b128 loads (L2-resident weights,
// no cross-wave reuse -> LDS staging was pure overhead).
//   mode 2: bf16 [b][h][n][32] head-major (Q, K) — LDS-staged coalesced out
//   mode 3: bf16 Vt[(b,h)*32+d][1024], phi-permuted n (V) — LDS transpose out
// ---------------------------------------------------------------------------
struct GemmArgs {
  const uint16_t* A[12];
  const uint16_t* W[12];
  const float*    bias[12];
  void*           C[12];
  float           os[12];
  int             mode[12];
};

DEVI void stage_A(const uint16_t* __restrict__ Ab, int m0, int kk,
                  char* AsB, int wid, int lane) {
  #pragma unroll
  for (int i = 0; i < 2; ++i) {
    const int seg = i * 4 + wid;                    // 16-row segment 0..7
    const int rl  = (seg << 4) + (lane >> 2);       // linear LDS row
    const int gs  = (lane & 3) ^ ((lane >> 3) & 3); // pre-swizzled src chunk
    const uint16_t* gA = Ab + (size_t)(m0 + rl) * 256 + kk + gs * 8;
    __builtin_amdgcn_global_load_lds(
        (const __attribute__((address_space(1))) void*)gA,
        (__attribute__((address_space(3))) void*)(AsB + (seg << 10)), 16, 0, 0);
  }
}

__global__ __launch_bounds__(256) void gemm_k(GemmArgs args) {
  const int z  = blockIdx.z;
  const int m0 = blockIdx.y * 128, n0 = blockIdx.x * 128;
  const uint16_t* Ab = args.A[z];
  const uint16_t* Wt = args.W[z];
  __shared__ __align__(16) uint16_t As[2][4096];   // [128][32] per buffer
  const int t = threadIdx.x;
  const int lane = t & 63, wid = t >> 6;
  const int g = lane >> 4, c = lane & 15;
  const int gx = g ^ ((c >> 1) & 3);               // swizzled LDS read chunk
  const int wm = (wid >> 1) * 64, wn = (wid & 1) * 64;
  f32x4 acc[4][4] = {};

  // B row pointers (direct global, plain g chunk)
  const uint16_t* bp[4];
  #pragma unroll
  for (int nt = 0; nt < 4; ++nt)
    bp[nt] = Wt + (size_t)(n0 + wn + nt * 16 + c) * 256 + g * 8;

  stage_A(Ab, m0, 0, (char*)As[0], wid, lane);
  __syncthreads();

  for (int ks = 0; ks < 8; ++ks) {
    const int buf = ks & 1;
    if (ks < 7)
      stage_A(Ab, m0, (ks + 1) * 32, (char*)As[buf ^ 1], wid, lane);
    bf16x8 af[4], bfr[4];
    #pragma unroll
    for (int nt = 0; nt < 4; ++nt)
      bfr[nt] = *(const bf16x8*)(bp[nt] + ks * 32);
    #pragma unroll
    for (int mt = 0; mt < 4; ++mt)
      af[mt]  = *(const bf16x8*)&As[buf][(wm + mt * 16 + c) * 32 + gx * 8];
    #pragma unroll
    for (int mt = 0; mt < 4; ++mt)
      #pragma unroll
      for (int nt = 0; nt < 4; ++nt)
        acc[mt][nt] = __builtin_amdgcn_mfma_f32_16x16x32_bf16(af[mt], bfr[nt], acc[mt][nt], 0, 0, 0);
    if (ks < 7) __syncthreads();
  }

  const float* bias = args.bias[z];
  const float osz = args.os[z];
  const int mode = args.mode[z];
  float bv[4];
  #pragma unroll
  for (int nt = 0; nt < 4; ++nt) bv[nt] = bias[n0 + wn + nt * 16 + c];

  if (mode == 2) {
    uint16_t* C = (uint16_t*)args.C[z];
    __syncthreads();
    uint16_t* ep = ((uint16_t*)As) + wid * (16 * 72);
    #pragma unroll
    for (int mt = 0; mt < 4; ++mt) {
      #pragma unroll
      for (int r = 0; r < 4; ++r)
        #pragma unroll
        for (int nt = 0; nt < 4; ++nt)
          ep[(4 * g + r) * 72 + nt * 16 + c] = f2bf((acc[mt][nt][r] + bv[nt]) * osz);
      #pragma unroll
      for (int sr = 0; sr < 2; ++sr) {
        const int row  = sr * 8 + (lane >> 3);
        const int col8 = (lane & 7) * 8;
        const uint4 v4 = *(const uint4*)&ep[row * 72 + col8];
        const int n  = m0 + wm + mt * 16 + row;
        const int bb = n >> 10, nn = n & 1023;
        const int colg = n0 + wn + col8;
        const int hh = colg >> 5, d = colg & 31;
        *(uint4*)&C[((size_t)(bb * 8 + hh) * 1024 + nn) * 32 + d] = v4;
      }
    }
  } else {
    uint16_t* C = (uint16_t*)args.C[z];
    __syncthreads();
    uint16_t* ep = ((uint16_t*)As) + wid * (64 * 24);
    const int colg = n0 + wn + lane;
    const int hh = colg >> 5, d = colg & 31;
    #pragma unroll
    for (int mt = 0; mt < 4; ++mt) {
      #pragma unroll
      for (int r = 0; r < 4; ++r) {
        const int pn = phi4(4 * g + r);
        #pragma unroll
        for (int nt = 0; nt < 4; ++nt)
          ep[(nt * 16 + c) * 24 + pn] = f2bf((acc[mt][nt][r] + bv[nt]) * osz);
      }
      const int nbase = m0 + wm + mt * 16;
      const int bb = nbase >> 10, nb = nbase & 1023;
      uint16_t* dst = C + ((size_t)(bb * 8 + hh) * 32 + d) * 1024 + nb;
      *(uint4*)dst       = *(const uint4*)&ep[lane * 24];
      *(uint4*)(dst + 8) = *(const uint4*)&ep[lane * 24 + 8];
    }
  }
}

// ---------------------------------------------------------------------------
// Fused masked flash attention — R10 config + s_setprio(1) around MFMA
// clusters (T5).  2 q-tiles/wave, split-K 2x, grid 1024.
// ---------------------------------------------------------------------------
struct AttnArgs {
  const uint16_t* Q[4];
  const uint16_t* K[4];
  const uint16_t* Vt[4];
  const uint32_t* adjb[4];   // transposed [b][kw][q]
  uint16_t*       O[4];
};

DEVI void soft_pv(f32x16& st, uint32_t w, float& l,
                  const bf16x8& vf0, const bf16x8& vf1, f32x16& oacc) {
  float s0 = 0.f, s1 = 0.f, s2 = 0.f, s3 = 0.f;
  #pragma unroll
  for (int r = 0; r < 16; ++r) {
    const int pos = (r & 3) + 8 * (r >> 2);
    const uint32_t msk = (uint32_t)__builtin_amdgcn_sbfe((int)w, pos, 1);
    const float pv = __uint_as_float(
        __float_as_uint(__builtin_amdgcn_exp2f(st[r])) & msk);
    st[r] = pv;
    if ((r & 3) == 0) s0 += pv; else if ((r & 3) == 1) s1 += pv;
    else if ((r & 3) == 2) s2 += pv; else s3 += pv;
  }
  l += (s0 + s1) + (s2 + s3);

  union PU { uint32_t u[4]; bf16x8 v; };
  PU p0, p1;
  p0.u[0] = packbf2(st[0],  st[1]);  p0.u[1] = packbf2(st[2],  st[3]);
  p0.u[2] = packbf2(st[4],  st[5]);  p0.u[3] = packbf2(st[6],  st[7]);
  p1.u[0] = packbf2(st[8],  st[9]);  p1.u[1] = packbf2(st[10], st[11]);
  p1.u[2] = packbf2(st[12], st[13]); p1.u[3] = packbf2(st[14], st[15]);

  __builtin_amdgcn_s_setprio(1);
  oacc = __builtin_amdgcn_mfma_f32_32x32x16_bf16(vf0, p0.v, oacc, 0, 0, 0);
  oacc = __builtin_amdgcn_mfma_f32_32x32x16_bf16(vf1, p1.v, oacc, 0, 0, 0);
  __builtin_amdgcn_s_setprio(0);
}

__global__ __launch_bounds__(256) void attn_k(AttnArgs args) {
  const int bid = blockIdx.x;
  const int qt  = bid >> 7;           // 8 q-tiles of 128 rows per group
  const int grp = bid & 127;          // (branch,b,h) -> same XCD
  const int bh = grp & 31, j = grp >> 5;
  const int b = bh >> 3, h = bh & 7;
  const int t = threadIdx.x, wid = t >> 6, lane = t & 63;
  const int qg = wid & 1, ks = wid >> 1;
  const int c = lane & 31, hi = lane >> 5;
  const int hsh = hi * 4;
  const int qrow = qt * 128 + qg * 64 + c;   // tile A; tile B = qrow+32

  const uint16_t* Qbh = args.Q[j] + (size_t)(b * 8 + h) * 32768;
  const uint16_t* Kbh = args.K[j] + (size_t)(b * 8 + h) * 32768;
  const uint16_t* Vbh = args.Vt[j] + ((size_t)(b * 8 + h) * 32 + c) * 1024 + hi * 8;

  const bf16x8 qa0 = *(const bf16x8*)&Qbh[qrow * 32 + hi * 8];
  const bf16x8 qa1 = *(const bf16x8*)&Qbh[qrow * 32 + 16 + hi * 8];
  const bf16x8 qb0 = *(const bf16x8*)&Qbh[(qrow + 32) * 32 + hi * 8];
  const bf16x8 qb1 = *(const bf16x8*)&Qbh[(qrow + 32) * 32 + 16 + hi * 8];

  f32x16 oA = {}, oB = {};
  float lA = 0.f, lB = 0.f;

  const int kbeg = ks * 512;
  const uint16_t* kp = Kbh + (size_t)(kbeg + c) * 32 + hi * 8;
  const uint16_t* vp = Vbh + kbeg;
  const uint32_t* ap = args.adjb[j] + (size_t)b * 32768
                       + ((size_t)(kbeg >> 5) << 10) + qrow;

  for (int it = 0; it < 16; ++it) {
    const uint32_t wA = ap[0]  >> hsh;
    const uint32_t wB = ap[32] >> hsh;
    const bf16x8 kf0 = *(const bf16x8*)kp;
    const bf16x8 kf1 = *(const bf16x8*)(kp + 16);
    const bf16x8 vf0 = *(const bf16x8*)vp;
    const bf16x8 vf1 = *(const bf16x8*)(vp + 16);
    ap += 1024; kp += 1024; vp += 32;

    f32x16 sA = {}, sB = {};
    __builtin_amdgcn_s_setprio(1);
    sA = __builtin_amdgcn_mfma_f32_32x32x16_bf16(kf0, qa0, sA, 0, 0, 0);
    sA = __builtin_amdgcn_mfma_f32_32x32x16_bf16(kf1, qa1, sA, 0, 0, 0);
    sB = __builtin_amdgcn_mfma_f32_32x32x16_bf16(kf0, qb0, sB, 0, 0, 0);
    sB = __builtin_amdgcn_mfma_f32_32x32x16_bf16(kf1, qb1, sB, 0, 0, 0);
    __builtin_amdgcn_s_setprio(0);

    soft_pv(sA, wA, lA, vf0, vf1, oA);
    soft_pv(sB, wB, lB, vf0, vf1, oB);
  }

  // ---- split-K combine (zero-shift partials add directly) -----------------
  __shared__ float red[2][2][64][17];
  if (ks == 1) {
    #pragma unroll
    for (int r = 0; r < 16; ++r) {
      red[qg][0][lane][r] = oA[r];
      red[qg][1][lane][r] = oB[r];
    }
    red[qg][0][lane][16] = lA;
    red[qg][1][lane][16] = lB;
  }
  __syncthreads();
  if (ks == 1) return;

  {
    #pragma unroll
    for (int r = 0; r < 16; ++r) {
      oA[r] += red[qg][0][lane][r];
      oB[r] += red[qg][1][lane][r];
    }
    lA += red[qg][0][lane][16];
    lB += red[qg][1][lane][16];
  }

  lA += __shfl_xor(lA, 32, 64);
  lB += __shfl_xor(lB, 32, 64);
  const float invA = 1.0f / lA;
  const float invB = 1.0f / lB;
  uint16_t* O = args.O[j];
  const size_t obA = (size_t)(b * 1024 + qrow) * 256 + h * 32 + 4 * hi;
  const size_t obB = obA + (size_t)32 * 256;
  #pragma unroll
  for (int rq = 0; rq < 4; ++rq) {
    uint2 vA, vB;
    vA.x = packbf2(oA[4*rq+0] * invA, oA[4*rq+1] * invA);
    vA.y = packbf2(oA[4*rq+2] * invA, oA[4*rq+3] * invA);
    vB.x = packbf2(oB[4*rq+0] * invB, oB[4*rq+1] * invB);
    vB.y = packbf2(oB[4*rq+2] * invB, oB[4*rq+3] * invB);
    *(uint2*)&O[obA + 8 * rq] = vA;
    *(uint2*)&O[obB + 8 * rq] = vB;
  }
}

// ---------------------------------------------------------------------------
// Fused O-proj (both branches of a side) + bias + residual + dual LN +
// relu-combine (+ final fp32 residual).  Block: 32 rows x 256 cols, 4 waves.
// B (Wo panels) read DIRECT from global (L2-resident); A via LDS dbuf.
// ---------------------------------------------------------------------------
struct OplnArgs {
  const uint16_t* A0[2]; const uint16_t* A1[2];     // attn outputs (branch pair)
  const uint16_t* W0[2]; const uint16_t* W1[2];     // Wo bf16 [n][k]
  const float*    b0[2]; const float*    b1[2];     // bo
  const uint16_t* res[2];                           // bf16 q_in residual
  const float* g0[2]; const float* be0[2];          // LN params branch 0
  const float* g1[2]; const float* be1[2];          // LN params branch 1
  const float* addin[2];                            // final fp32 residual or null
  float*     outf[2];                               // fp32 out or null
  uint16_t*  outbf[2];                              // bf16 mirror or null
};

__global__ __launch_bounds__(256) void opln_k(OplnArgs args) {
  const int side = blockIdx.y;
  const int m0 = blockIdx.x * 32;
  const uint16_t* A0 = args.A0[side];
  const uint16_t* A1 = args.A1[side];
  const uint16_t* W0 = args.W0[side];
  const uint16_t* W1 = args.W1[side];

  __shared__ __align__(16) char lds[20480];
  uint16_t* As0 = (uint16_t*)(lds);                 // 2 buf x 1024 elems (4KB)
  uint16_t* As1 = (uint16_t*)(lds + 4096);          // 4KB
  uint16_t* outt = (uint16_t*)lds;                  // [32][272] aliases stage
  float*    red = (float*)(lds + 17664);            // [32][4][4]
  float*    muv = (float*)(lds + 19712);            // [32][4]

  const int t = threadIdx.x;
  const int lane = t & 63, wid = t >> 6;
  const int g = lane >> 4, c = lane & 15;
  const int gx = g ^ ((c >> 1) & 3);
  const int gs = (lane & 3) ^ ((lane >> 3) & 3);

  auto stageA = [&](int buf, int kk) {
    // wave wid stages seg (wid&1) of matrix (wid>>1)
    const uint16_t* src = (wid < 2) ? A0 : A1;
    char* dst = (char*)((wid < 2) ? As0 : As1) + (size_t)buf * 2048 + ((wid & 1) << 10);
    const int rl = ((wid & 1) << 4) + (lane >> 2);
    __builtin_amdgcn_global_load_lds(
        (const __attribute__((address_space(1))) void*)(src + (size_t)(m0 + rl) * 256 + kk + gs * 8),
        (__attribute__((address_space(3))) void*)dst, 16, 0, 0);
  };

  // B row pointers (direct global)
  const uint16_t* bp0[4];
  const uint16_t* bp1[4];
  #pragma unroll
  for (int nt = 0; nt < 4; ++nt) {
    bp0[nt] = W0 + (size_t)(wid * 64 + nt * 16 + c) * 256 + g * 8;
    bp1[nt] = W1 + (size_t)(wid * 64 + nt * 16 + c) * 256 + g * 8;
  }

  f32x4 a0[2][4] = {}, a1[2][4] = {};
  stageA(0, 0);
  __syncthreads();

  for (int ks = 0; ks < 8; ++ks) {
    const int buf = ks & 1;
    if (ks < 7) stageA(buf ^ 1, (ks + 1) * 32);
    const uint16_t* As0b = As0 + buf * 1024;
    const uint16_t* As1b = As1 + buf * 1024;
    bf16x8 fa0[2], fa1[2], fb0[4], fb1[4];
    #pragma unroll
    for (int nt = 0; nt < 4; ++nt) {
      fb0[nt] = *(const bf16x8*)(bp0[nt] + ks * 32);
      fb1[nt] = *(const bf16x8*)(bp1[nt] + ks * 32);
    }
    #pragma unroll
    for (int mt = 0; mt < 2; ++mt) {
      fa0[mt] = *(const bf16x8*)&As0b[(mt * 16 + c) * 32 + gx * 8];
      fa1[mt] = *(const bf16x8*)&As1b[(mt * 16 + c) * 32 + gx * 8];
    }
    #pragma unroll
    for (int mt = 0; mt < 2; ++mt)
      #pragma unroll
      for (int nt = 0; nt < 4; ++nt) {
        a0[mt][nt] = __builtin_amdgcn_mfma_f32_16x16x32_bf16(fa0[mt], fb0[nt], a0[mt][nt], 0, 0, 0);
        a1[mt][nt] = __builtin_amdgcn_mfma_f32_16x16x32_bf16(fa1[mt], fb1[nt], a1[mt][nt], 0, 0, 0);
      }
    if (ks < 7) __syncthreads();
  }

  // ---- x = acc + bias + residual (fp32, in place) ----
  const float* b0p = args.b0[side];
  const float* b1p = args.b1[side];
  const uint16_t* resp = args.res[side];
  float bv0[4], bv1[4];
  #pragma unroll
  for (int nt = 0; nt < 4; ++nt) {
    bv0[nt] = b0p[wid * 64 + nt * 16 + c];
    bv1[nt] = b1p[wid * 64 + nt * 16 + c];
  }
  #pragma unroll
  for (int mt = 0; mt < 2; ++mt)
    #pragma unroll
    for (int r = 0; r < 4; ++r) {
      const int row = mt * 16 + 4 * g + r;
      #pragma unroll
      for (int nt = 0; nt < 4; ++nt) {
        const float rf = bf2f(resp[(size_t)(m0 + row) * 256 + wid * 64 + nt * 16 + c]);
        a0[mt][nt][r] = a0[mt][nt][r] + bv0[nt] + rf;
        a1[mt][nt][r] = a1[mt][nt][r] + bv1[nt] + rf;
      }
    }

  // ---- per-row partial sums over this wave's 64 cols ----
  #pragma unroll
  for (int mt = 0; mt < 2; ++mt)
    #pragma unroll
    for (int r = 0; r < 4; ++r) {
      float s0 = 0.f, ss0 = 0.f, s1 = 0.f, ss1 = 0.f;
      #pragma unroll
      for (int nt = 0; nt < 4; ++nt) {
        const float x0 = a0[mt][nt][r], x1 = a1[mt][nt][r];
        s0 += x0; ss0 += x0 * x0; s1 += x1; ss1 += x1 * x1;
      }
      #pragma unroll
      for (int m = 1; m < 16; m <<= 1) {
        s0 += __shfl_xor(s0, m, 64);  ss0 += __shfl_xor(ss0, m, 64);
        s1 += __shfl_xor(s1, m, 64);  ss1 += __shfl_xor(ss1, m, 64);
      }
      if (c == 0) {
        const int row = mt * 16 + 4 * g + r;
        float* rp = red + (row * 4 + wid) * 4;
        rp[0] = s0; rp[1] = ss0; rp[2] = s1; rp[3] = ss1;
      }
    }
  __syncthreads();

  if (t < 32) {
    float S0 = 0.f, SS0 = 0.f, S1 = 0.f, SS1 = 0.f;
    #pragma unroll
    for (int w = 0; w < 4; ++w) {
      const float* rp = red + (t * 4 + w) * 4;
      S0 += rp[0]; SS0 += rp[1]; S1 += rp[2]; SS1 += rp[3];
    }
    const float mu0 = S0 * (1.f / 256.f);
    const float mu1 = S1 * (1.f / 256.f);
    const float rs0 = rsqrtf(SS0 * (1.f / 256.f) - mu0 * mu0 + 1e-5f);
    const float rs1 = rsqrtf(SS1 * (1.f / 256.f) - mu1 * mu1 + 1e-5f);
    float* mp = muv + t * 4;
    mp[0] = mu0; mp[1] = rs0; mp[2] = mu1; mp[3] = rs1;
  }
  __syncthreads();

  // ---- y = relu(LN0(x0) + LN1(x1)) -> bf16 LDS tile ----
  const float* g0p = args.g0[side];  const float* be0p = args.be0[side];
  const float* g1p = args.g1[side];  const float* be1p = args.be1[side];
  float ga0[4], bb0[4], ga1[4], bb1[4];
  #pragma unroll
  for (int nt = 0; nt < 4; ++nt) {
    const int col = wid * 64 + nt * 16 + c;
    ga0[nt] = g0p[col]; bb0[nt] = be0p[col];
    ga1[nt] = g1p[col]; bb1[nt] = be1p[col];
  }
  #pragma unroll
  for (int mt = 0; mt < 2; ++mt)
    #pragma unroll
    for (int r = 0; r < 4; ++r) {
      const int row = mt * 16 + 4 * g + r;
      const float4 m4 = *(const float4*)(muv + row * 4);
      #pragma unroll
      for (int nt = 0; nt < 4; ++nt) {
        const float y = fmaxf((a0[mt][nt][r] - m4.x) * m4.y * ga0[nt] + bb0[nt]
                            + (a1[mt][nt][r] - m4.z) * m4.w * ga1[nt] + bb1[nt], 0.f);
        outt[row * 272 + wid * 64 + nt * 16 + c] = f2bf(y);
      }
    }
  __syncthreads();

  // ---- coalesced writeback ----
  const int orow = t >> 3, ocb = (t & 7) * 32;
  if (args.addin[side]) {
    const float* ad = args.addin[side] + (size_t)(m0 + orow) * 256 + ocb;
    float* of = args.outf[side] + (size_t)(m0 + orow) * 256 + ocb;
    #pragma unroll
    for (int q = 0; q < 8; ++q) {
      const float4 av = *(const float4*)(ad + q * 4);
      float4 y4;
      y4.x = bf2f(outt[orow * 272 + ocb + q * 4 + 0]) + av.x;
      y4.y = bf2f(outt[orow * 272 + ocb + q * 4 + 1]) + av.y;
      y4.z = bf2f(outt[orow * 272 + ocb + q * 4 + 2]) + av.z;
      y4.w = bf2f(outt[orow * 272 + ocb + q * 4 + 3]) + av.w;
      *(float4*)(of + q * 4) = y4;
    }
  } else {
    uint16_t* ob = args.outbf[side] + (size_t)(m0 + orow) * 256 + ocb;
    #pragma unroll
    for (int q = 0; q < 4; ++q)
      *(uint4*)(ob + q * 8) = *(const uint4*)&outt[orow * 272 + ocb + q * 8];
  }
}

// ---------------------------------------------------------------------------
// Host launch
// ---------------------------------------------------------------------------
extern "C" void kernel_launch(void* const* d_in, const int* in_sizes, int n_in,
                              void* d_out, int out_size, void* d_ws, size_t ws_size,
                              hipStream_t stream) {
  (void)in_sizes; (void)n_in; (void)out_size; (void)ws_size;
  const float* h_a = (const float*)d_in[0];
  const float* h_b = (const float*)d_in[1];
  const float* bq  = (const float*)d_in[7];
  const float* bk  = (const float*)d_in[9];
  const float* bv  = (const float*)d_in[11];
  const float* bo  = (const float*)d_in[13];
  const float* lng = (const float*)d_in[14];
  const float* lnb = (const float*)d_in[15];

  // log2(e)/sqrt(dk): folds softmax scale + exp->exp2 into Q projection
  const float QSC = 1.4426950408889634f * 0.17677669529663687f;

  char* ws = (char*)d_ws;
  uint16_t* WT   = (uint16_t*)ws;                        // 0-4 MB
  uint32_t* ADJB = (uint32_t*)(ws + (4u  << 20));        // 4-6 MB (transposed)
  uint16_t* hAbf = (uint16_t*)(ws + (6u  << 20));        // 6-8 MB
  uint16_t* hBbf = (uint16_t*)(ws + (8u  << 20));        // 8-10 MB
  uint16_t* Qb[4]; uint16_t* Kb[4]; uint16_t* Vtb[4]; uint16_t* ATb[4];
  for (int j = 0; j < 4; ++j) {
    Qb[j]  = (uint16_t*)(ws + (10u << 20) + (size_t)j * (2u << 20));  // 10-18
    Kb[j]  = (uint16_t*)(ws + (18u << 20) + (size_t)j * (2u << 20));  // 18-26
    Vtb[j] = (uint16_t*)(ws + (26u << 20) + (size_t)j * (2u << 20));  // 26-34
    ATb[j] = (uint16_t*)(ws + (34u << 20) + (size_t)j * (2u << 20));  // 34-42
  }

  {
    PrepArgs pa;
    pa.Wq = (const float*)d_in[6];  pa.Wk = (const float*)d_in[8];
    pa.Wv = (const float*)d_in[10]; pa.Wo = (const float*)d_in[12];
    pa.wt = WT;
    pa.ha = h_a; pa.hb = h_b; pa.oa = hAbf; pa.ob = hBbf;
    for (int j = 0; j < 4; ++j) {
      pa.adj[j]  = (const int*)d_in[2 + j];
      pa.bits[j] = ADJB + (size_t)j * 131072;
    }
    prep_k<<<dim3(67072, 1, 1), 256, 0, stream>>>(pa);
  }

  for (int i = 0; i < 2; ++i) {
    const uint16_t* qbf[4]  = { hAbf, hBbf, hBbf, hAbf };   // a2a, b2b, a2b, b2a
    const uint16_t* kvbf[4] = { hAbf, hBbf, hAbf, hBbf };

    {
      GemmArgs ga = {};
      for (int j = 0; j < 4; ++j) {
        const int mm = i * 4 + j;
        ga.A[j]     = qbf[j];  ga.W[j]     = WT + 0 * 524288 + (size_t)mm * 65536;
        ga.bias[j]  = bq + mm * 256; ga.C[j] = Qb[j];  ga.os[j] = QSC;  ga.mode[j] = 2;
        ga.A[4+j]   = kvbf[j]; ga.W[4+j]   = WT + 1 * 524288 + (size_t)mm * 65536;
        ga.bias[4+j]= bk + mm * 256; ga.C[4+j] = Kb[j]; ga.os[4+j] = 1.0f; ga.mode[4+j] = 2;
        ga.A[8+j]   = kvbf[j]; ga.W[8+j]   = WT + 2 * 524288 + (size_t)mm * 65536;
        ga.bias[8+j]= bv + mm * 256; ga.C[8+j] = Vtb[j]; ga.os[8+j] = 1.0f; ga.mode[8+j] = 3;
      }
      gemm_k<<<dim3(2, 32, 12), 256, 0, stream>>>(ga);
    }
    {
      AttnArgs at;
      for (int j = 0; j < 4; ++j) {
        at.Q[j] = Qb[j]; at.K[j] = Kb[j]; at.Vt[j] = Vtb[j];
        at.adjb[j] = ADJB + (size_t)j * 131072; at.O[j] = ATb[j];
      }
      attn_k<<<dim3(1024, 1, 1), 256, 0, stream>>>(at);
    }
    {
      // side 0 (out a): branches 0 (a2a) + 3 (b2a), residual hAbf
      // side 1 (out b): branches 1 (b2b) + 2 (a2b), residual hBbf
      OplnArgs oa;
      const int j0[2] = {0, 1}, j1[2] = {3, 2};
      for (int s = 0; s < 2; ++s) {
        const int mm0 = i * 4 + j0[s], mm1 = i * 4 + j1[s];
        oa.A0[s] = ATb[j0[s]];  oa.A1[s] = ATb[j1[s]];
        oa.W0[s] = WT + 3 * 524288 + (size_t)mm0 * 65536;
        oa.W1[s] = WT + 3 * 524288 + (size_t)mm1 * 65536;
        oa.b0[s] = bo + mm0 * 256;  oa.b1[s] = bo + mm1 * 256;
        oa.res[s] = s ? hBbf : hAbf;
        oa.g0[s] = lng + mm0 * 256;  oa.be0[s] = lnb + mm0 * 256;
        oa.g1[s] = lng + mm1 * 256;  oa.be1[s] = lnb + mm1 * 256;
        if (i == 1) {
          oa.addin[s] = s ? h_b : h_a;
          oa.outf[s]  = (float*)d_out + (size_t)s * 1048576;
          oa.outbf[s] = nullptr;
        } else {
          oa.addin[s] = nullptr;
          oa.outf[s]  = nullptr;
          oa.outbf[s] = s ? hBbf : hAbf;
        }
      }
      opln_k<<<dim3(128, 2), 256, 0, stream>>>(oa);
    }
  }
}

// Round 17
// 186.360 us; speedup vs baseline: 1.1026x; 1.1026x over previous
//
#include <hip/hip_runtime.h>
#include <hip/hip_bf16.h>
#include <stdint.h>

// ---------------------------------------------------------------------------
// Co-Guiding GAT forward: 2 layers x 4 masked-MHA branches, B=4 N=1024 D=256
// H=8 dk=32.
// R17: R16 retry with CORRECT B-stage offsets (R16 bug: seg<<9/buf*8192
// overlapped segments; each 64-lane gload_lds = 1024B, B buffer = 16384B).
// opln_k M-tile 16 -> grid (256,2) = 512 blocks = 2 blocks/CU.
// Rest identical to R14 (best passing, 186.7us).
// ---------------------------------------------------------------------------

using bf16x8 = __attribute__((ext_vector_type(8))) short;   // 8 bf16 (4 VGPRs)
using f32x4  = __attribute__((ext_vector_type(4))) float;
using f32x16 = __attribute__((ext_vector_type(16))) float;

#define DEVI __device__ __forceinline__

DEVI uint16_t f2bf(float x) {                 // RNE f32 -> bf16 bits (scalar)
  uint32_t u = __float_as_uint(x);
  u += 0x7FFFu + ((u >> 16) & 1u);
  return (uint16_t)(u >> 16);
}
DEVI uint32_t packbf2(float lo, float hi) {   // hw v_cvt_pk_bf16_f32 via API
  union { __hip_bfloat162 h; uint32_t u; } cv;
  cv.h = __float22bfloat162_rn(make_float2(lo, hi));
  return cv.u;
}
DEVI float bf2f(uint16_t v) { return __uint_as_float((uint32_t)v << 16); }
DEVI int phi4(int m) {                        // swap bits 2<->3 (involution)
  return ((m & 4) << 1) | ((m & 8) >> 1) | (m & 3);
}

// ---------------------------------------------------------------------------
// Merged prep: blocks [0,512) weight transpose+cvt; [512,1536) input cvt;
// [1536,67072) adjacency -> transposed bitmask.
// ---------------------------------------------------------------------------
struct PrepArgs {
  const float* Wq; const float* Wk; const float* Wv; const float* Wo;
  uint16_t* wt;
  const float* ha; const float* hb;
  uint16_t* oa; uint16_t* ob;
  const int* adj[4];
  uint32_t* bits[4];
};

__global__ __launch_bounds__(256) void prep_k(PrepArgs a) {
  const int blk = blockIdx.x;
  const int t = threadIdx.x;
  __shared__ float tl[64][68];

  if (blk < 512) {               // ---- weight prep ----
    const int bx = blk & 3, by = (blk >> 2) & 3, z = blk >> 4;
    const int type = z >> 3, mat = z & 7;
    const float* W = (type == 0 ? a.Wq : type == 1 ? a.Wk : type == 2 ? a.Wv : a.Wo)
                     + (size_t)mat * 65536;
    uint16_t* o = a.wt + (size_t)type * 524288 + (size_t)mat * 65536;
    const int r0 = by * 64, c0 = bx * 64;
    {
      const int rr = t >> 2, cb = (t & 3) * 16;
      const float* src = W + (size_t)(r0 + rr) * 256 + c0 + cb;
      #pragma unroll
      for (int q = 0; q < 4; ++q) {
        float4 v = *(const float4*)(src + q * 4);
        tl[rr][cb + q*4 + 0] = v.x; tl[rr][cb + q*4 + 1] = v.y;
        tl[rr][cb + q*4 + 2] = v.z; tl[rr][cb + q*4 + 3] = v.w;
      }
    }
    __syncthreads();
    {
      const int nn = t >> 2, kb = (t & 3) * 16;
      __align__(16) uint16_t tmp[16];
      #pragma unroll
      for (int q = 0; q < 16; ++q) tmp[q] = f2bf(tl[kb + q][nn]);
      uint16_t* dst = o + (size_t)(c0 + nn) * 256 + r0 + kb;
      *(uint4*)&dst[0] = *(uint4*)&tmp[0];
      *(uint4*)&dst[8] = *(uint4*)&tmp[8];
    }
  } else if (blk < 1536) {       // ---- input fp32->bf16 ----
    const int idx = blk - 512;
    const int bx = idx & 511, by = idx >> 9;
    const size_t i = ((size_t)bx * 256 + t) * 8;
    const float* s = by ? a.hb : a.ha;
    uint16_t* o = by ? a.ob : a.oa;
    const float4 f0 = *(const float4*)(s + i), f1 = *(const float4*)(s + i + 4);
    uint4 u;
    u.x = packbf2(f0.x, f0.y); u.y = packbf2(f0.z, f0.w);
    u.z = packbf2(f1.x, f1.y); u.w = packbf2(f1.z, f1.w);
    *(uint4*)(o + i) = u;
  } else {                       // ---- adj -> bitmask ----
    const int idx = blk - 1536;
    const int bx = idx & 16383, z = idx >> 14;
    const int* adj = a.adj[z];
    uint32_t* bits = a.bits[z];
    const size_t i = (size_t)bx * 256 + t;
    const int lane = t & 63;
    const int v = adj[i];
    unsigned long long m = __ballot(v != 0);
    if ((lane & 31) == 0) {
      const uint32_t wi = (uint32_t)(i >> 5);      // (b*1024+q)*32 + kw
      const uint32_t kw = wi & 31;
      const uint32_t q  = (wi >> 5) & 1023;
      const uint32_t bb = wi >> 15;
      bits[((bb * 32 + kw) << 10) | q] = (uint32_t)(m >> (lane & 32));
    }
  }
}

// ---------------------------------------------------------------------------
// GEMM (QKV): C = (Abf @ W + bias) * os, epilogue mode per z (R14 version:
// A and B both LDS double-buffered via global_load_lds, swizzled reads).
//   mode 2: bf16 [b][h][n][32] head-major (Q, K) — LDS-staged coalesced
//   mode 3: bf16 Vt[(b,h)*32+d][1024], phi-permuted n (V) — LDS transpose
// ---------------------------------------------------------------------------
struct GemmArgs {
  const uint16_t* A[12];
  const uint16_t* W[12];
  const float*    bias[12];
  void*           C[12];
  float           os[12];
  int             mode[12];
};

DEVI void stage_tile(const uint16_t* __restrict__ Ab,
                     const uint16_t* __restrict__ Wt,
                     int m0, int n0, int kk,
                     char* AsB, char* BsB, int wid, int lane) {
  #pragma unroll
  for (int i = 0; i < 2; ++i) {
    const int seg = i * 4 + wid;                    // 16-row segment 0..7
    const int rl  = (seg << 4) + (lane >> 2);       // linear LDS row
    const int gs  = (lane & 3) ^ ((lane >> 3) & 3); // pre-swizzled src chunk
    const uint16_t* gA = Ab + (size_t)(m0 + rl) * 256 + kk + gs * 8;
    const uint16_t* gB = Wt + (size_t)(n0 + rl) * 256 + kk + gs * 8;
    __builtin_amdgcn_global_load_lds(
        (const __attribute__((address_space(1))) void*)gA,
        (__attribute__((address_space(3))) void*)(AsB + (seg << 10)), 16, 0, 0);
    __builtin_amdgcn_global_load_lds(
        (const __attribute__((address_space(1))) void*)gB,
        (__attribute__((address_space(3))) void*)(BsB + (seg << 10)), 16, 0, 0);
  }
}

__global__ __launch_bounds__(256) void gemm_k(GemmArgs args) {
  const int z  = blockIdx.z;
  const int m0 = blockIdx.y * 128, n0 = blockIdx.x * 128;
  const uint16_t* Ab = args.A[z];
  const uint16_t* Wt = args.W[z];
  __shared__ __align__(16) uint16_t As[2][4096];   // [128][32] per buffer
  __shared__ __align__(16) uint16_t Bs[2][4096];
  const int t = threadIdx.x;
  const int lane = t & 63, wid = t >> 6;
  const int g = lane >> 4, c = lane & 15;
  const int gx = g ^ ((c >> 1) & 3);               // swizzled read chunk
  const int wm = (wid >> 1) * 64, wn = (wid & 1) * 64;
  f32x4 acc[4][4] = {};

  stage_tile(Ab, Wt, m0, n0, 0, (char*)As[0], (char*)Bs[0], wid, lane);
  __syncthreads();

  for (int ks = 0; ks < 8; ++ks) {
    const int buf = ks & 1;
    if (ks < 7)
      stage_tile(Ab, Wt, m0, n0, (ks + 1) * 32,
                 (char*)As[buf ^ 1], (char*)Bs[buf ^ 1], wid, lane);
    bf16x8 af[4], bfr[4];
    #pragma unroll
    for (int mt = 0; mt < 4; ++mt)
      af[mt]  = *(const bf16x8*)&As[buf][(wm + mt * 16 + c) * 32 + gx * 8];
    #pragma unroll
    for (int nt = 0; nt < 4; ++nt)
      bfr[nt] = *(const bf16x8*)&Bs[buf][(wn + nt * 16 + c) * 32 + gx * 8];
    #pragma unroll
    for (int mt = 0; mt < 4; ++mt)
      #pragma unroll
      for (int nt = 0; nt < 4; ++nt)
        acc[mt][nt] = __builtin_amdgcn_mfma_f32_16x16x32_bf16(af[mt], bfr[nt], acc[mt][nt], 0, 0, 0);
    if (ks < 7) __syncthreads();
  }

  const float* bias = args.bias[z];
  const float osz = args.os[z];
  const int mode = args.mode[z];
  float bv[4];
  #pragma unroll
  for (int nt = 0; nt < 4; ++nt) bv[nt] = bias[n0 + wn + nt * 16 + c];

  if (mode == 2) {
    uint16_t* C = (uint16_t*)args.C[z];
    __syncthreads();
    uint16_t* ep = ((uint16_t*)As) + wid * (16 * 72);
    #pragma unroll
    for (int mt = 0; mt < 4; ++mt) {
      #pragma unroll
      for (int r = 0; r < 4; ++r)
        #pragma unroll
        for (int nt = 0; nt < 4; ++nt)
          ep[(4 * g + r) * 72 + nt * 16 + c] = f2bf((acc[mt][nt][r] + bv[nt]) * osz);
      #pragma unroll
      for (int sr = 0; sr < 2; ++sr) {
        const int row  = sr * 8 + (lane >> 3);
        const int col8 = (lane & 7) * 8;
        const uint4 v4 = *(const uint4*)&ep[row * 72 + col8];
        const int n  = m0 + wm + mt * 16 + row;
        const int bb = n >> 10, nn = n & 1023;
        const int colg = n0 + wn + col8;
        const int hh = colg >> 5, d = colg & 31;
        *(uint4*)&C[((size_t)(bb * 8 + hh) * 1024 + nn) * 32 + d] = v4;
      }
    }
  } else {
    uint16_t* C = (uint16_t*)args.C[z];
    __syncthreads();
    uint16_t* ep = ((uint16_t*)As) + wid * (64 * 24);
    const int colg = n0 + wn + lane;
    const int hh = colg >> 5, d = colg & 31;
    #pragma unroll
    for (int mt = 0; mt < 4; ++mt) {
      #pragma unroll
      for (int r = 0; r < 4; ++r) {
        const int pn = phi4(4 * g + r);
        #pragma unroll
        for (int nt = 0; nt < 4; ++nt)
          ep[(nt * 16 + c) * 24 + pn] = f2bf((acc[mt][nt][r] + bv[nt]) * osz);
      }
      const int nbase = m0 + wm + mt * 16;
      const int bb = nbase >> 10, nb = nbase & 1023;
      uint16_t* dst = C + ((size_t)(bb * 8 + hh) * 32 + d) * 1024 + nb;
      *(uint4*)dst       = *(const uint4*)&ep[lane * 24];
      *(uint4*)(dst + 8) = *(const uint4*)&ep[lane * 24 + 8];
    }
  }
}

// ---------------------------------------------------------------------------
// Fused masked flash attention — R14 config (R10 structure, pipelined loads,
// NO setprio): 32x32 MFMA, zero-C softmax, split-K 2x, 2 q-tiles/wave.
// ---------------------------------------------------------------------------
struct AttnArgs {
  const uint16_t* Q[4];
  const uint16_t* K[4];
  const uint16_t* Vt[4];
  const uint32_t* adjb[4];   // transposed [b][kw][q]
  uint16_t*       O[4];
};

DEVI void soft_pv(f32x16& st, uint32_t w, float& l,
                  const bf16x8& vf0, const bf16x8& vf1, f32x16& oacc) {
  float s0 = 0.f, s1 = 0.f, s2 = 0.f, s3 = 0.f;
  #pragma unroll
  for (int r = 0; r < 16; ++r) {
    const int pos = (r & 3) + 8 * (r >> 2);
    const uint32_t msk = (uint32_t)__builtin_amdgcn_sbfe((int)w, pos, 1);
    const float pv = __uint_as_float(
        __float_as_uint(__builtin_amdgcn_exp2f(st[r])) & msk);
    st[r] = pv;
    if ((r & 3) == 0) s0 += pv; else if ((r & 3) == 1) s1 += pv;
    else if ((r & 3) == 2) s2 += pv; else s3 += pv;
  }
  l += (s0 + s1) + (s2 + s3);

  union PU { uint32_t u[4]; bf16x8 v; };
  PU p0, p1;
  p0.u[0] = packbf2(st[0],  st[1]);  p0.u[1] = packbf2(st[2],  st[3]);
  p0.u[2] = packbf2(st[4],  st[5]);  p0.u[3] = packbf2(st[6],  st[7]);
  p1.u[0] = packbf2(st[8],  st[9]);  p1.u[1] = packbf2(st[10], st[11]);
  p1.u[2] = packbf2(st[12], st[13]); p1.u[3] = packbf2(st[14], st[15]);

  oacc = __builtin_amdgcn_mfma_f32_32x32x16_bf16(vf0, p0.v, oacc, 0, 0, 0);
  oacc = __builtin_amdgcn_mfma_f32_32x32x16_bf16(vf1, p1.v, oacc, 0, 0, 0);
}

__global__ __launch_bounds__(256) void attn_k(AttnArgs args) {
  const int bid = blockIdx.x;
  const int qt  = bid >> 7;           // 8 q-tiles of 128 rows per group
  const int grp = bid & 127;          // (branch,b,h) -> same XCD
  const int bh = grp & 31, j = grp >> 5;
  const int b = bh >> 3, h = bh & 7;
  const int t = threadIdx.x, wid = t >> 6, lane = t & 63;
  const int qg = wid & 1, ks = wid >> 1;
  const int c = lane & 31, hi = lane >> 5;
  const int hsh = hi * 4;
  const int qrow = qt * 128 + qg * 64 + c;   // tile A; tile B = qrow+32

  const uint16_t* Qbh = args.Q[j] + (size_t)(b * 8 + h) * 32768;
  const uint16_t* Kbh = args.K[j] + (size_t)(b * 8 + h) * 32768;
  const uint16_t* Vbh = args.Vt[j] + ((size_t)(b * 8 + h) * 32 + c) * 1024 + hi * 8;

  const bf16x8 qa0 = *(const bf16x8*)&Qbh[qrow * 32 + hi * 8];
  const bf16x8 qa1 = *(const bf16x8*)&Qbh[qrow * 32 + 16 + hi * 8];
  const bf16x8 qb0 = *(const bf16x8*)&Qbh[(qrow + 32) * 32 + hi * 8];
  const bf16x8 qb1 = *(const bf16x8*)&Qbh[(qrow + 32) * 32 + 16 + hi * 8];

  f32x16 oA = {}, oB = {};
  float lA = 0.f, lB = 0.f;

  const int kbeg = ks * 512;
  const uint16_t* kp = Kbh + (size_t)(kbeg + c) * 32 + hi * 8;
  const uint16_t* vp = Vbh + kbeg;
  const uint32_t* ap = args.adjb[j] + (size_t)b * 32768
                       + ((size_t)(kbeg >> 5) << 10) + qrow;

  // prologue loads (iteration 0 operands)
  uint32_t wA = ap[0]  >> hsh;
  uint32_t wB = ap[32] >> hsh;
  bf16x8 kf0 = *(const bf16x8*)kp;
  bf16x8 kf1 = *(const bf16x8*)(kp + 16);
  bf16x8 vf0 = *(const bf16x8*)vp;
  bf16x8 vf1 = *(const bf16x8*)(vp + 16);

  for (int it = 0; it < 16; ++it) {
    // issue next-iteration loads first (latency hides under soft_pv);
    // last iteration over-reads into adjacent ws buffers (allocated, unused).
    ap += 1024; kp += 1024; vp += 32;
    const uint32_t nwA = ap[0]  >> hsh;
    const uint32_t nwB = ap[32] >> hsh;
    const bf16x8 nk0 = *(const bf16x8*)kp;
    const bf16x8 nk1 = *(const bf16x8*)(kp + 16);
    const bf16x8 nv0 = *(const bf16x8*)vp;
    const bf16x8 nv1 = *(const bf16x8*)(vp + 16);

    f32x16 sA = {};
    sA = __builtin_amdgcn_mfma_f32_32x32x16_bf16(kf0, qa0, sA, 0, 0, 0);
    sA = __builtin_amdgcn_mfma_f32_32x32x16_bf16(kf1, qa1, sA, 0, 0, 0);
    soft_pv(sA, wA, lA, vf0, vf1, oA);

    f32x16 sB = {};
    sB = __builtin_amdgcn_mfma_f32_32x32x16_bf16(kf0, qb0, sB, 0, 0, 0);
    sB = __builtin_amdgcn_mfma_f32_32x32x16_bf16(kf1, qb1, sB, 0, 0, 0);
    soft_pv(sB, wB, lB, vf0, vf1, oB);

    wA = nwA; wB = nwB; kf0 = nk0; kf1 = nk1; vf0 = nv0; vf1 = nv1;
  }

  // ---- split-K combine (zero-shift partials add directly) -----------------
  __shared__ float red[2][2][64][17];
  if (ks == 1) {
    #pragma unroll
    for (int r = 0; r < 16; ++r) {
      red[qg][0][lane][r] = oA[r];
      red[qg][1][lane][r] = oB[r];
    }
    red[qg][0][lane][16] = lA;
    red[qg][1][lane][16] = lB;
  }
  __syncthreads();
  if (ks == 1) return;

  {
    #pragma unroll
    for (int r = 0; r < 16; ++r) {
      oA[r] += red[qg][0][lane][r];
      oB[r] += red[qg][1][lane][r];
    }
    lA += red[qg][0][lane][16];
    lB += red[qg][1][lane][16];
  }

  lA += __shfl_xor(lA, 32, 64);
  lB += __shfl_xor(lB, 32, 64);
  const float invA = 1.0f / lA;
  const float invB = 1.0f / lB;
  uint16_t* O = args.O[j];
  const size_t obA = (size_t)(b * 1024 + qrow) * 256 + h * 32 + 4 * hi;
  const size_t obB = obA + (size_t)32 * 256;
  #pragma unroll
  for (int rq = 0; rq < 4; ++rq) {
    uint2 vA, vB;
    vA.x = packbf2(oA[4*rq+0] * invA, oA[4*rq+1] * invA);
    vA.y = packbf2(oA[4*rq+2] * invA, oA[4*rq+3] * invA);
    vB.x = packbf2(oB[4*rq+0] * invB, oB[4*rq+1] * invB);
    vB.y = packbf2(oB[4*rq+2] * invB, oB[4*rq+3] * invB);
    *(uint2*)&O[obA + 8 * rq] = vA;
    *(uint2*)&O[obB + 8 * rq] = vB;
  }
}

// ---------------------------------------------------------------------------
// Fused O-proj (both branches of a side) + bias + residual + dual LN +
// relu-combine (+ final fp32 residual).  M-tile 16, grid (256,2) = 512
// blocks = 2 blocks/CU.  Block: 16 rows x 256 cols, 4 waves.
// LDS map (bytes): As0 0..2048 (2buf x 1024), As1 2048..4096,
// Bs0 4096..36864 (2buf x 16384), Bs1 36864..69632, red 69632..70656,
// muv 70656..70912.  outt [16][272] (8704B) aliases bytes 0..8704 (dead
// stage regions; written only after post-MFMA barriers).
// ---------------------------------------------------------------------------
struct OplnArgs {
  const uint16_t* A0[2]; const uint16_t* A1[2];     // attn outputs (branch pair)
  const uint16_t* W0[2]; const uint16_t* W1[2];     // Wo bf16 [n][k]
  const float*    b0[2]; const float*    b1[2];     // bo
  const uint16_t* res[2];                           // bf16 q_in residual
  const float* g0[2]; const float* be0[2];          // LN params branch 0
  const float* g1[2]; const float* be1[2];          // LN params branch 1
  const float* addin[2];                            // final fp32 residual or null
  float*     outf[2];                               // fp32 out or null
  uint16_t*  outbf[2];                              // bf16 mirror or null
};

__global__ __launch_bounds__(256) void opln_k(OplnArgs args) {
  const int side = blockIdx.y;
  const int m0 = blockIdx.x * 16;
  const uint16_t* A0 = args.A0[side];
  const uint16_t* A1 = args.A1[side];
  const uint16_t* W0 = args.W0[side];
  const uint16_t* W1 = args.W1[side];

  __shared__ __align__(16) char lds[70912];
  uint16_t* As0 = (uint16_t*)(lds);                 // 2 buf x 512 elems
  uint16_t* As1 = (uint16_t*)(lds + 2048);
  uint16_t* Bs0 = (uint16_t*)(lds + 4096);          // 2 buf x 8192 elems
  uint16_t* Bs1 = (uint16_t*)(lds + 36864);
  float*    red = (float*)(lds + 69632);            // [16][4][4]
  float*    muv = (float*)(lds + 70656);            // [16][4]
  uint16_t* outt = (uint16_t*)lds;                  // [16][272] (aliases stage)

  const int t = threadIdx.x;
  const int lane = t & 63, wid = t >> 6;
  const int g = lane >> 4, c = lane & 15;
  const int gx = g ^ ((c >> 1) & 3);
  const int gs = (lane & 3) ^ ((lane >> 3) & 3);

  auto stage = [&](int buf, int kk) {
    // A: waves 0,2 each stage the full 16-row tile of their matrix (1024B)
    if ((wid & 1) == 0) {
      const uint16_t* src = (wid < 2) ? A0 : A1;
      char* dst = (char*)((wid < 2) ? As0 : As1) + (size_t)buf * 1024;
      const int rl = lane >> 2;
      __builtin_amdgcn_global_load_lds(
          (const __attribute__((address_space(1))) void*)(src + (size_t)(m0 + rl) * 256 + kk + gs * 8),
          (__attribute__((address_space(3))) void*)dst, 16, 0, 0);
    }
    #pragma unroll
    for (int i = 0; i < 8; ++i) {   // B: 32 segs of 16 rows (16 per matrix)
      const int s32 = i * 4 + wid;
      const int mat = s32 >> 4, seg = s32 & 15;
      const uint16_t* src = mat ? W1 : W0;
      char* dst = (char*)(mat ? Bs1 : Bs0) + (size_t)buf * 16384 + (seg << 10);
      const int rl = (seg << 4) + (lane >> 2);
      __builtin_amdgcn_global_load_lds(
          (const __attribute__((address_space(1))) void*)(src + (size_t)rl * 256 + kk + gs * 8),
          (__attribute__((address_space(3))) void*)dst, 16, 0, 0);
    }
  };

  f32x4 a0[4] = {}, a1[4] = {};
  stage(0, 0);
  __syncthreads();

  for (int ks = 0; ks < 8; ++ks) {
    const int buf = ks & 1;
    if (ks < 7) stage(buf ^ 1, (ks + 1) * 32);
    const uint16_t* As0b = As0 + buf * 512;
    const uint16_t* As1b = As1 + buf * 512;
    const uint16_t* Bs0b = Bs0 + buf * 8192;
    const uint16_t* Bs1b = Bs1 + buf * 8192;
    bf16x8 fa0, fa1, fb0[4], fb1[4];
    fa0 = *(const bf16x8*)&As0b[c * 32 + gx * 8];
    fa1 = *(const bf16x8*)&As1b[c * 32 + gx * 8];
    #pragma unroll
    for (int nt = 0; nt < 4; ++nt) {
      fb0[nt] = *(const bf16x8*)&Bs0b[(wid * 64 + nt * 16 + c) * 32 + gx * 8];
      fb1[nt] = *(const bf16x8*)&Bs1b[(wid * 64 + nt * 16 + c) * 32 + gx * 8];
    }
    #pragma unroll
    for (int nt = 0; nt < 4; ++nt) {
      a0[nt] = __builtin_amdgcn_mfma_f32_16x16x32_bf16(fa0, fb0[nt], a0[nt], 0, 0, 0);
      a1[nt] = __builtin_amdgcn_mfma_f32_16x16x32_bf16(fa1, fb1[nt], a1[nt], 0, 0, 0);
    }
    if (ks < 7) __syncthreads();
  }

  // ---- x = acc + bias + residual (fp32, in place) ----
  const float* b0p = args.b0[side];
  const float* b1p = args.b1[side];
  const uint16_t* resp = args.res[side];
  float bv0[4], bv1[4];
  #pragma unroll
  for (int nt = 0; nt < 4; ++nt) {
    bv0[nt] = b0p[wid * 64 + nt * 16 + c];
    bv1[nt] = b1p[wid * 64 + nt * 16 + c];
  }
  #pragma unroll
  for (int r = 0; r < 4; ++r) {
    const int row = 4 * g + r;
    #pragma unroll
    for (int nt = 0; nt < 4; ++nt) {
      const float rf = bf2f(resp[(size_t)(m0 + row) * 256 + wid * 64 + nt * 16 + c]);
      a0[nt][r] = a0[nt][r] + bv0[nt] + rf;
      a1[nt][r] = a1[nt][r] + bv1[nt] + rf;
    }
  }

  // ---- per-row partial sums over this wave's 64 cols ----
  #pragma unroll
  for (int r = 0; r < 4; ++r) {
    float s0 = 0.f, ss0 = 0.f, s1 = 0.f, ss1 = 0.f;
    #pragma unroll
    for (int nt = 0; nt < 4; ++nt) {
      const float x0 = a0[nt][r], x1 = a1[nt][r];
      s0 += x0; ss0 += x0 * x0; s1 += x1; ss1 += x1 * x1;
    }
    #pragma unroll
    for (int m = 1; m < 16; m <<= 1) {
      s0 += __shfl_xor(s0, m, 64);  ss0 += __shfl_xor(ss0, m, 64);
      s1 += __shfl_xor(s1, m, 64);  ss1 += __shfl_xor(ss1, m, 64);
    }
    if (c == 0) {
      const int row = 4 * g + r;
      float* rp = red + (row * 4 + wid) * 4;
      rp[0] = s0; rp[1] = ss0; rp[2] = s1; rp[3] = ss1;
    }
  }
  __syncthreads();

  if (t < 16) {
    float S0 = 0.f, SS0 = 0.f, S1 = 0.f, SS1 = 0.f;
    #pragma unroll
    for (int w = 0; w < 4; ++w) {
      const float* rp = red + (t * 4 + w) * 4;
      S0 += rp[0]; SS0 += rp[1]; S1 += rp[2]; SS1 += rp[3];
    }
    const float mu0 = S0 * (1.f / 256.f);
    const float mu1 = S1 * (1.f / 256.f);
    const float rs0 = rsqrtf(SS0 * (1.f / 256.f) - mu0 * mu0 + 1e-5f);
    const float rs1 = rsqrtf(SS1 * (1.f / 256.f) - mu1 * mu1 + 1e-5f);
    float* mp = muv + t * 4;
    mp[0] = mu0; mp[1] = rs0; mp[2] = mu1; mp[3] = rs1;
  }
  __syncthreads();

  // ---- y = relu(LN0(x0) + LN1(x1)) -> bf16 LDS tile ----
  const float* g0p = args.g0[side];  const float* be0p = args.be0[side];
  const float* g1p = args.g1[side];  const float* be1p = args.be1[side];
  float ga0[4], bb0[4], ga1[4], bb1[4];
  #pragma unroll
  for (int nt = 0; nt < 4; ++nt) {
    const int col = wid * 64 + nt * 16 + c;
    ga0[nt] = g0p[col]; bb0[nt] = be0p[col];
    ga1[nt] = g1p[col]; bb1[nt] = be1p[col];
  }
  #pragma unroll
  for (int r = 0; r < 4; ++r) {
    const int row = 4 * g + r;
    const float4 m4 = *(const float4*)(muv + row * 4);
    #pragma unroll
    for (int nt = 0; nt < 4; ++nt) {
      const float y = fmaxf((a0[nt][r] - m4.x) * m4.y * ga0[nt] + bb0[nt]
                          + (a1[nt][r] - m4.z) * m4.w * ga1[nt] + bb1[nt], 0.f);
      outt[row * 272 + wid * 64 + nt * 16 + c] = f2bf(y);
    }
  }
  __syncthreads();

  // ---- coalesced writeback (16 rows x 256 cols; 16 threads/row) ----
  const int orow = t >> 4, oc = (t & 15) * 16;
  if (args.addin[side]) {
    const float* ad = args.addin[side] + (size_t)(m0 + orow) * 256 + oc;
    float* of = args.outf[side] + (size_t)(m0 + orow) * 256 + oc;
    #pragma unroll
    for (int q = 0; q < 4; ++q) {
      const float4 av = *(const float4*)(ad + q * 4);
      float4 y4;
      y4.x = bf2f(outt[orow * 272 + oc + q * 4 + 0]) + av.x;
      y4.y = bf2f(outt[orow * 272 + oc + q * 4 + 1]) + av.y;
      y4.z = bf2f(outt[orow * 272 + oc + q * 4 + 2]) + av.z;
      y4.w = bf2f(outt[orow * 272 + oc + q * 4 + 3]) + av.w;
      *(float4*)(of + q * 4) = y4;
    }
  } else {
    uint16_t* ob = args.outbf[side] + (size_t)(m0 + orow) * 256 + oc;
    *(uint4*)(ob + 0) = *(const uint4*)&outt[orow * 272 + oc + 0];
    *(uint4*)(ob + 8) = *(const uint4*)&outt[orow * 272 + oc + 8];
  }
}

// ---------------------------------------------------------------------------
// Host launch
// ---------------------------------------------------------------------------
extern "C" void kernel_launch(void* const* d_in, const int* in_sizes, int n_in,
                              void* d_out, int out_size, void* d_ws, size_t ws_size,
                              hipStream_t stream) {
  (void)in_sizes; (void)n_in; (void)out_size; (void)ws_size;
  const float* h_a = (const float*)d_in[0];
  const float* h_b = (const float*)d_in[1];
  const float* bq  = (const float*)d_in[7];
  const float* bk  = (const float*)d_in[9];
  const float* bv  = (const float*)d_in[11];
  const float* bo  = (const float*)d_in[13];
  const float* lng = (const float*)d_in[14];
  const float* lnb = (const float*)d_in[15];

  // log2(e)/sqrt(dk): folds softmax scale + exp->exp2 into Q projection
  const float QSC = 1.4426950408889634f * 0.17677669529663687f;

  char* ws = (char*)d_ws;
  uint16_t* WT   = (uint16_t*)ws;                        // 0-4 MB
  uint32_t* ADJB = (uint32_t*)(ws + (4u  << 20));        // 4-6 MB (transposed)
  uint16_t* hAbf = (uint16_t*)(ws + (6u  << 20));        // 6-8 MB
  uint16_t* hBbf = (uint16_t*)(ws + (8u  << 20));        // 8-10 MB
  uint16_t* Qb[4]; uint16_t* Kb[4]; uint16_t* Vtb[4]; uint16_t* ATb[4];
  for (int j = 0; j < 4; ++j) {
    Qb[j]  = (uint16_t*)(ws + (10u << 20) + (size_t)j * (2u << 20));  // 10-18
    Kb[j]  = (uint16_t*)(ws + (18u << 20) + (size_t)j * (2u << 20));  // 18-26
    Vtb[j] = (uint16_t*)(ws + (26u << 20) + (size_t)j * (2u << 20));  // 26-34
    ATb[j] = (uint16_t*)(ws + (34u << 20) + (size_t)j * (2u << 20));  // 34-42
  }

  {
    PrepArgs pa;
    pa.Wq = (const float*)d_in[6];  pa.Wk = (const float*)d_in[8];
    pa.Wv = (const float*)d_in[10]; pa.Wo = (const float*)d_in[12];
    pa.wt = WT;
    pa.ha = h_a; pa.hb = h_b; pa.oa = hAbf; pa.ob = hBbf;
    for (int j = 0; j < 4; ++j) {
      pa.adj[j]  = (const int*)d_in[2 + j];
      pa.bits[j] = ADJB + (size_t)j * 131072;
    }
    prep_k<<<dim3(67072, 1, 1), 256, 0, stream>>>(pa);
  }

  for (int i = 0; i < 2; ++i) {
    const uint16_t* qbf[4]  = { hAbf, hBbf, hBbf, hAbf };   // a2a, b2b, a2b, b2a
    const uint16_t* kvbf[4] = { hAbf, hBbf, hAbf, hBbf };

    {
      GemmArgs ga = {};
      for (int j = 0; j < 4; ++j) {
        const int mm = i * 4 + j;
        ga.A[j]     = qbf[j];  ga.W[j]     = WT + 0 * 524288 + (size_t)mm * 65536;
        ga.bias[j]  = bq + mm * 256; ga.C[j] = Qb[j];  ga.os[j] = QSC;  ga.mode[j] = 2;
        ga.A[4+j]   = kvbf[j]; ga.W[4+j]   = WT + 1 * 524288 + (size_t)mm * 65536;
        ga.bias[4+j]= bk + mm * 256; ga.C[4+j] = Kb[j]; ga.os[4+j] = 1.0f; ga.mode[4+j] = 2;
        ga.A[8+j]   = kvbf[j]; ga.W[8+j]   = WT + 2 * 524288 + (size_t)mm * 65536;
        ga.bias[8+j]= bv + mm * 256; ga.C[8+j] = Vtb[j]; ga.os[8+j] = 1.0f; ga.mode[8+j] = 3;
      }
      gemm_k<<<dim3(2, 32, 12), 256, 0, stream>>>(ga);
    }
    {
      AttnArgs at;
      for (int j = 0; j < 4; ++j) {
        at.Q[j] = Qb[j]; at.K[j] = Kb[j]; at.Vt[j] = Vtb[j];
        at.adjb[j] = ADJB + (size_t)j * 131072; at.O[j] = ATb[j];
      }
      attn_k<<<dim3(1024, 1, 1), 256, 0, stream>>>(at);
    }
    {
      // side 0 (out a): branches 0 (a2a) + 3 (b2a), residual hAbf
      // side 1 (out b): branches 1 (b2b) + 2 (a2b), residual hBbf
      OplnArgs oa;
      const int j0[2] = {0, 1}, j1[2] = {3, 2};
      for (int s = 0; s < 2; ++s) {
        const int mm0 = i * 4 + j0[s], mm1 = i * 4 + j1[s];
        oa.A0[s] = ATb[j0[s]];  oa.A1[s] = ATb[j1[s]];
        oa.W0[s] = WT + 3 * 524288 + (size_t)mm0 * 65536;
        oa.W1[s] = WT + 3 * 524288 + (size_t)mm1 * 65536;
        oa.b0[s] = bo + mm0 * 256;  oa.b1[s] = bo + mm1 * 256;
        oa.res[s] = s ? hBbf : hAbf;
        oa.g0[s] = lng + mm0 * 256;  oa.be0[s] = lnb + mm0 * 256;
        oa.g1[s] = lng + mm1 * 256;  oa.be1[s] = lnb + mm1 * 256;
        if (i == 1) {
          oa.addin[s] = s ? h_b : h_a;
          oa.outf[s]  = (float*)d_out + (size_t)s * 1048576;
          oa.outbf[s] = nullptr;
        } else {
          oa.addin[s] = nullptr;
          oa.outf[s]  = nullptr;
          oa.outbf[s] = s ? hBbf : hAbf;
        }
      }
      opln_k<<<dim3(256, 2), 256, 0, stream>>>(oa);
    }
  }
}